// Round 6
// baseline (1804.017 us; speedup 1.0000x reference)
//
#include <hip/hip_runtime.h>

// ---------------------------------------------------------------------------
// 3-state pair-HMM forward DP (logsumexp semiring), skewed band pipeline v3.
//   12 bands x 128 rows; one 64-lane wave per band; lane L owns rows
//   128b+2L+1, +2 and computes a 2x2 cell block per step (4 cells).
// R6: R3/R4/R5 all measured ~700-900 cy/cell == one memory latency per cell:
//   the compiler sinks register "prefetch" loads to their uses (VGPR 96-136,
//   far below buffer footprint), defeating software pipelining. Fix: stage
//   theta through LDS with __builtin_amdgcn_global_load_lds (un-sinkable,
//   zero VGPR) at distance 4 steps, with an explicit s_waitcnt vmcnt(38)
//   before consuming a slot. 8 LDS slots x 9248 B = 74 KB.
//   Theta pre-packed to skew layout [b][t][lane][36] (verified in R5).
// ---------------------------------------------------------------------------

#define MM    1536
#define NB    12
#define MP    768                 // column pairs per row
#define STEPS 832                 // 104 blocks * 8 steps; last active t = 830
#define TBLK  104
#define NSLOT 8
#define SLOTB 9248                // 9216 theta + 32 feed
#define DIST  4
#define LOG2E 1.4426950408889634f
#define LN2   0.6931471805599453f
#define NEG2  (-1.4426950408889634e8f)   // (-1e8)*LOG2E, log2-domain -inf

#define PK_BYTES  ((size_t)NB * STEPS * 64 * 36 * 4)   // 91,963,392
#define BOT_BYTES ((size_t)NB * (MM + 1) * 4 * 4)      // 295,104

// s_waitcnt imm: vmcnt=n (6-bit split), lgkmcnt/expcnt unconstrained
#define VMCNT_IMM(n) ((((n) >> 4) << 14) | 0x0F00 | 0x0070 | ((n) & 0xF))

static __device__ __forceinline__ float lse3_2(float a, float b, float c) {
    float mx = fmaxf(fmaxf(a, b), c);
    float mn = fminf(fminf(a, b), c);
    float md = __builtin_amdgcn_fmed3f(a, b, c);
    return mx + __builtin_amdgcn_logf(1.0f + __builtin_amdgcn_exp2f(mn - mx)
                                           + __builtin_amdgcn_exp2f(md - mx));
}

static __device__ __forceinline__ void gl_lds16(const void* g, void* l) {
    __builtin_amdgcn_global_load_lds(
        (const __attribute__((address_space(1))) void*)g,
        (__attribute__((address_space(3))) void*)l, 16, 0, 0);
}

__global__ void init_progress_kernel(int* progress) {
    if (threadIdx.x < NB) progress[threadIdx.x] = -1;
}

// packed[((b*STEPS+t)*64+L)*36]: theta for (m = t-L):
//  [0..8] th[rowA-1][2m] | [9..17] th[rowA-1][2m+1]
//  [18..26] th[rowB-1][2m] | [27..35] th[rowB-1][2m+1],
//  rowA-1 = 128b+2L, rowB-1 = 128b+2L+1 (0-indexed theta rows).
__global__ __launch_bounds__(64)
void pack_kernel(const float* __restrict__ theta, float* __restrict__ packed) {
    const int bt = blockIdx.x;
    const int b  = bt / STEPS;
    const int t  = bt - b * STEPS;
    const int L  = threadIdx.x;
    const int m  = t - L;
    float* dst = (float*)__builtin_assume_aligned(packed, 16)
                 + ((size_t)bt * 64 + L) * 36;
    if (m >= 0 && m < MP) {
        const int rA0 = b * 128 + 2 * L;
        __builtin_memcpy(dst,      theta + ((size_t)rA0 * MM + 2 * m) * 9, 72);
        __builtin_memcpy(dst + 18, theta + ((size_t)(rA0 + 1) * MM + 2 * m) * 9, 72);
    } else {
        #pragma unroll
        for (int i = 0; i < 36; ++i) dst[i] = 0.0f;
    }
}

__global__ __launch_bounds__(64, 1)
void hmm_fwd_lds(const float* __restrict__ packed, float* __restrict__ out,
                 float* __restrict__ bottom, int* __restrict__ progress)
{
    __shared__ __align__(16) char lds[NSLOT * SLOTB];
    const int b = blockIdx.x;
    const int L = threadIdx.x;

    const float* __restrict__ bsrc =
        bottom + (size_t)(b > 0 ? b - 1 : 0) * ((MM + 1) * 4);
    float* __restrict__ bdst = bottom + (size_t)b * ((MM + 1) * 4);

    // state (log2 domain): pd=V[rA-1][2m], pu1=V[rA-1][2m+1], pu2=V[rA-1][2m+2]
    //                      la=V[rA][2m], lb=V[rB][2m]
    float pd0, pd1, pd2, pu10, pu11, pu12, pu20, pu21, pu22;
    float la0, la1, la2, lb0, lb1, lb2, res0, res1, res2;
    pd0 = pd1 = pd2 = (b == 0 && L == 0) ? 0.0f : NEG2;   // V[0][0] = 0
    pu10 = pu11 = pu12 = NEG2;  pu20 = pu21 = pu22 = NEG2;
    la0 = la1 = la2 = NEG2;     lb0 = lb1 = lb2 = NEG2;
    res0 = res1 = res2 = NEG2;

    if (b > 0) {
        // cover feed cols <= 42 (pre-loop prime + blocks t0=0,8) until the
        // first in-loop poll at t0=16
        while (__hip_atomic_load(&progress[b - 1], __ATOMIC_ACQUIRE,
                                 __HIP_MEMORY_SCOPE_AGENT) < 48)
            __builtin_amdgcn_s_sleep(2);
        float ta[4], tb[4];
        __builtin_memcpy(ta, bsrc + 4, 16);   // col 1
        __builtin_memcpy(tb, bsrc + 8, 16);   // col 2
        pu10 = (L == 0) ? ta[0] : NEG2;
        pu11 = (L == 0) ? ta[1] : NEG2;
        pu12 = (L == 0) ? ta[2] : NEG2;
        pu20 = (L == 0) ? tb[0] : NEG2;
        pu21 = (L == 0) ? tb[1] : NEG2;
        pu22 = (L == 0) ? tb[2] : NEG2;
    }

    // issue the staging batch for target step t (clamped): 9x16B theta + feed
    auto issue_batch = [&](int t) {
        int tc = t < STEPS ? t : STEPS - 1;
        const float* gp = packed + ((size_t)(b * STEPS + tc) * 64 + L) * 36;
        char* sb = lds + (size_t)(tc & (NSLOT - 1)) * SLOTB;
        #pragma unroll
        for (int c = 0; c < 9; ++c)
            gl_lds16(gp + c * 4, sb + c * 1024);
        if (b > 0 && L < 2) {
            int jn = 2 * tc + 3 + L;          // feed cols 2t+3, 2t+4
            if (jn > MM) jn = MM;
            gl_lds16(bsrc + (size_t)jn * 4, sb + 9216);
        }
    };

    issue_batch(0); issue_batch(1); issue_batch(2); issue_batch(3);

    for (int tb = 0; tb < TBLK; ++tb) {
        const int t0 = tb * 8;

        // producer publish at block start (release drains only stale loads)
        if (b < NB - 1 && t0 >= 64 && L == 0) {
            int val = 2 * t0 - 126;           // cols done through step t0-1
            if (val > MM) val = MM;
            __hip_atomic_store(&progress[b], val, __ATOMIC_RELEASE,
                               __HIP_MEMORY_SCOPE_AGENT);
        }
        // consumer poll every 16 steps: covers feed issues through col 2t0+42
        if (b > 0 && t0 > 0 && (t0 & 15) == 0) {
            int need = 2 * t0 + 42; if (need > MM) need = MM;
            while (__hip_atomic_load(&progress[b - 1], __ATOMIC_ACQUIRE,
                                     __HIP_MEMORY_SCOPE_AGENT) < need)
                __builtin_amdgcn_s_sleep(2);
        }

        #pragma unroll
        for (int k = 0; k < 8; ++k) {
            const int t = t0 + k;

            issue_batch(t + DIST);
            // wait until <=38 VMEM outstanding: slot t (issued 4 steps ago,
            // >=41 newer ops since) is guaranteed complete; slots t+1..t+4
            // stay in flight.
            __builtin_amdgcn_s_waitcnt(VMCNT_IMM(38));

            const char* sb = lds + (size_t)(t & (NSLOT - 1)) * SLOTB;
            float g[36];
            #pragma unroll
            for (int c = 0; c < 9; ++c) {
                float4 q = *(const float4*)(sb + c * 1024 + L * 16);
                g[c * 4 + 0] = q.x; g[c * 4 + 1] = q.y;
                g[c * 4 + 2] = q.z; g[c * 4 + 3] = q.w;
            }
            float4 ffa = *(const float4*)(sb + 9216);   // col 2t+3 (broadcast)
            float4 ffb = *(const float4*)(sb + 9232);   // col 2t+4

            const int m = t - L;
            const bool act = (m >= 0) && (m < MP);

            float x0, x1, x2;
            // A1 (rowA, col 2m+1): diag=pd, up=pu1, left=la
            x0 = fmaf(g[0], LOG2E, pd0);  x1 = fmaf(g[1], LOG2E, pd1);  x2 = fmaf(g[2], LOG2E, pd2);
            float nA1_0 = lse3_2(x0, x1, x2);
            x0 = fmaf(g[3], LOG2E, pu10); x1 = fmaf(g[4], LOG2E, pu11); x2 = fmaf(g[5], LOG2E, pu12);
            float nA1_1 = lse3_2(x0, x1, x2);
            x0 = fmaf(g[6], LOG2E, la0);  x1 = fmaf(g[7], LOG2E, la1);  x2 = fmaf(g[8], LOG2E, la2);
            float nA1_2 = lse3_2(x0, x1, x2);
            // A2 (rowA, col 2m+2): diag=pu1, up=pu2, left=nA1
            x0 = fmaf(g[9],  LOG2E, pu10); x1 = fmaf(g[10], LOG2E, pu11); x2 = fmaf(g[11], LOG2E, pu12);
            float nA2_0 = lse3_2(x0, x1, x2);
            x0 = fmaf(g[12], LOG2E, pu20); x1 = fmaf(g[13], LOG2E, pu21); x2 = fmaf(g[14], LOG2E, pu22);
            float nA2_1 = lse3_2(x0, x1, x2);
            x0 = fmaf(g[15], LOG2E, nA1_0); x1 = fmaf(g[16], LOG2E, nA1_1); x2 = fmaf(g[17], LOG2E, nA1_2);
            float nA2_2 = lse3_2(x0, x1, x2);
            // B1 (rowB, col 2m+1): diag=la, up=nA1, left=lb
            x0 = fmaf(g[18], LOG2E, la0);  x1 = fmaf(g[19], LOG2E, la1);  x2 = fmaf(g[20], LOG2E, la2);
            float nB1_0 = lse3_2(x0, x1, x2);
            x0 = fmaf(g[21], LOG2E, nA1_0); x1 = fmaf(g[22], LOG2E, nA1_1); x2 = fmaf(g[23], LOG2E, nA1_2);
            float nB1_1 = lse3_2(x0, x1, x2);
            x0 = fmaf(g[24], LOG2E, lb0);  x1 = fmaf(g[25], LOG2E, lb1);  x2 = fmaf(g[26], LOG2E, lb2);
            float nB1_2 = lse3_2(x0, x1, x2);
            // B2 (rowB, col 2m+2): diag=nA1, up=nA2, left=nB1
            x0 = fmaf(g[27], LOG2E, nA1_0); x1 = fmaf(g[28], LOG2E, nA1_1); x2 = fmaf(g[29], LOG2E, nA1_2);
            float nB2_0 = lse3_2(x0, x1, x2);
            x0 = fmaf(g[30], LOG2E, nA2_0); x1 = fmaf(g[31], LOG2E, nA2_1); x2 = fmaf(g[32], LOG2E, nA2_2);
            float nB2_1 = lse3_2(x0, x1, x2);
            x0 = fmaf(g[33], LOG2E, nB1_0); x1 = fmaf(g[34], LOG2E, nB1_1); x2 = fmaf(g[35], LOG2E, nB1_2);
            float nB2_2 = lse3_2(x0, x1, x2);

            // mask escaping values
            nA2_0 = act ? nA2_0 : NEG2; nA2_1 = act ? nA2_1 : NEG2; nA2_2 = act ? nA2_2 : NEG2;
            nB1_0 = act ? nB1_0 : NEG2; nB1_1 = act ? nB1_1 : NEG2; nB1_2 = act ? nB1_2 : NEG2;
            nB2_0 = act ? nB2_0 : NEG2; nB2_1 = act ? nB2_1 : NEG2; nB2_2 = act ? nB2_2 : NEG2;

            // producer: lane 63's rowB is the band's bottom row
            if (b < NB - 1 && L == 63 && act) {
                float st[8] = {nB1_0, nB1_1, nB1_2, 0.0f,
                               nB2_0, nB2_1, nB2_2, 0.0f};
                __builtin_memcpy(bdst + (size_t)(2 * m + 1) * 4, st, 32);
            }
            if (b == NB - 1) {
                const bool fin = (L == 63) && (t == 830);   // m = 767
                res0 = fin ? nB2_0 : res0;
                res1 = fin ? nB2_1 : res1;
                res2 = fin ? nB2_2 : res2;
            }

            // rotate state for step t+1
            float opu20 = pu20, opu21 = pu21, opu22 = pu22;
            float s0 = __shfl_up(nB1_0, 1, 64);
            float s1 = __shfl_up(nB1_1, 1, 64);
            float s2 = __shfl_up(nB1_2, 1, 64);
            float s3 = __shfl_up(nB2_0, 1, 64);
            float s4 = __shfl_up(nB2_1, 1, 64);
            float s5 = __shfl_up(nB2_2, 1, 64);
            pu10 = (L == 0) ? (b > 0 ? ffa.x : NEG2) : s0;
            pu11 = (L == 0) ? (b > 0 ? ffa.y : NEG2) : s1;
            pu12 = (L == 0) ? (b > 0 ? ffa.z : NEG2) : s2;
            pu20 = (L == 0) ? (b > 0 ? ffb.x : NEG2) : s3;
            pu21 = (L == 0) ? (b > 0 ? ffb.y : NEG2) : s4;
            pu22 = (L == 0) ? (b > 0 ? ffb.z : NEG2) : s5;
            pd0 = opu20; pd1 = opu21; pd2 = opu22;
            la0 = nA2_0; la1 = nA2_1; la2 = nA2_2;
            lb0 = nB2_0; lb1 = nB2_1; lb2 = nB2_2;
        }
    }

    if (b < NB - 1) {
        if (L == 0)
            __hip_atomic_store(&progress[b], MM, __ATOMIC_RELEASE,
                               __HIP_MEMORY_SCOPE_AGENT);
    } else if (L == 63) {
        out[0] = LN2 * lse3_2(res0, res1, res2);
    }
}

extern "C" void kernel_launch(void* const* d_in, const int* in_sizes, int n_in,
                              void* d_out, int out_size, void* d_ws, size_t ws_size,
                              hipStream_t stream)
{
    const float* theta = (const float*)d_in[0];
    float* out = (float*)d_out;

    float* packed   = (float*)d_ws;
    float* bottom   = (float*)((char*)d_ws + PK_BYTES);
    int*   progress = (int*)((char*)d_ws + PK_BYTES + BOT_BYTES);

    init_progress_kernel<<<1, 64, 0, stream>>>(progress);
    pack_kernel<<<NB * STEPS, 64, 0, stream>>>(theta, packed);
    hmm_fwd_lds<<<NB, 64, 0, stream>>>(packed, out, bottom, progress);
}